// Round 1
// baseline (2115.815 us; speedup 1.0000x reference)
//
#include <hip/hip_runtime.h>

typedef __attribute__((ext_vector_type(8))) __bf16 bf16x8;
typedef __attribute__((ext_vector_type(4))) float f32x4;

#define NMOD 5
#define H 512
#define BSZ 16384

__device__ inline float wred(float v) {
    #pragma unroll
    for (int o = 32; o; o >>= 1) v += __shfl_xor(v, o, 64);
    return v;
}

// ---------------------------------------------------------------------------
// Tiled bf16 MFMA GEMM: C[M,N] = A[M,K] @ B[K,N] (+ epilogue)
// Block 256 thr = 4 waves; tile 64x64, BK=32; wave -> 32x32 (2x2 mfma 16x16x32)
// EPI: 0 = none->bf16, 1 = bias+relu->bf16, 2 = bias+residual->bf16,
//      3 = bias->bf16, 4 = bias->f32
// AF32: A is fp32 in global (convert during staging), else bf16.
// B is always fp32 (original weights), converted during staging.
// z-batched via blockIdx.z with element strides sAz/sBz/sBiasz/sResz/sCz.
// ---------------------------------------------------------------------------
#define BM 64
#define BN 64
#define BK 32
#define LP 40   // LDS row stride (elems): +8 pad, keeps 16B alignment

template<int EPI, bool AF32>
__global__ __launch_bounds__(256)
void gemm_k(const void* __restrict__ Ag, long long sAz, int lda,
            const float* __restrict__ Bg, long long sBz, int ldb,
            const float* __restrict__ biasg, long long sBiasz,
            const __bf16* __restrict__ resg, long long sResz, int ldr,
            void* __restrict__ Cg, long long sCz, int ldc, int K)
{
    __shared__ __bf16 As[BM][LP];
    __shared__ __bf16 Bs[BN][LP];   // stored transposed: Bs[n][k]
    const int tid  = threadIdx.x;
    const int lane = tid & 63;
    const int wave = tid >> 6;
    const int wm = wave >> 1;
    const int wn = wave & 1;
    const int z = blockIdx.z;
    const long long bm0 = (long long)blockIdx.y * BM;
    const long long bn0 = (long long)blockIdx.x * BN;

    const float*  Af = AF32 ? ((const float*)Ag + (long long)z * sAz) : nullptr;
    const __bf16* Ah = AF32 ? nullptr : ((const __bf16*)Ag + (long long)z * sAz);
    const float*  Bp = Bg + (long long)z * sBz;

    const int ar = tid >> 2, ac = (tid & 3) * 8;   // A staging: row, 8-col group
    const int bk = tid >> 3, bn = (tid & 7) * 8;   // B staging: k, 8-n group

    const f32x4 zero4 = {0.f, 0.f, 0.f, 0.f};
    f32x4 acc[2][2];
    acc[0][0] = zero4; acc[0][1] = zero4; acc[1][0] = zero4; acc[1][1] = zero4;

    const int q8  = (lane >> 4) * 8;   // k-offset of this lane's fragment
    const int r16 = lane & 15;         // m (A) / n (B) index within 16-tile

    for (int k0 = 0; k0 < K; k0 += BK) {
        if (AF32) {
            const float* s = Af + (bm0 + ar) * (long long)lda + (k0 + ac);
            float4 f0 = *(const float4*)s;
            float4 f1 = *(const float4*)(s + 4);
            bf16x8 t;
            t[0] = (__bf16)f0.x; t[1] = (__bf16)f0.y; t[2] = (__bf16)f0.z; t[3] = (__bf16)f0.w;
            t[4] = (__bf16)f1.x; t[5] = (__bf16)f1.y; t[6] = (__bf16)f1.z; t[7] = (__bf16)f1.w;
            *(bf16x8*)&As[ar][ac] = t;
        } else {
            *(bf16x8*)&As[ar][ac] =
                *(const bf16x8*)(Ah + (bm0 + ar) * (long long)lda + (k0 + ac));
        }
        {
            const float* s = Bp + (long long)(k0 + bk) * ldb + (bn0 + bn);
            float4 f0 = *(const float4*)s;
            float4 f1 = *(const float4*)(s + 4);
            __bf16 t[8] = {(__bf16)f0.x, (__bf16)f0.y, (__bf16)f0.z, (__bf16)f0.w,
                           (__bf16)f1.x, (__bf16)f1.y, (__bf16)f1.z, (__bf16)f1.w};
            #pragma unroll
            for (int i = 0; i < 8; i++) Bs[bn + i][bk] = t[i];
        }
        __syncthreads();
        bf16x8 a0 = *(const bf16x8*)&As[wm * 32 +  0 + r16][q8];
        bf16x8 a1 = *(const bf16x8*)&As[wm * 32 + 16 + r16][q8];
        bf16x8 b0 = *(const bf16x8*)&Bs[wn * 32 +  0 + r16][q8];
        bf16x8 b1 = *(const bf16x8*)&Bs[wn * 32 + 16 + r16][q8];
        acc[0][0] = __builtin_amdgcn_mfma_f32_16x16x32_bf16(a0, b0, acc[0][0], 0, 0, 0);
        acc[0][1] = __builtin_amdgcn_mfma_f32_16x16x32_bf16(a0, b1, acc[0][1], 0, 0, 0);
        acc[1][0] = __builtin_amdgcn_mfma_f32_16x16x32_bf16(a1, b0, acc[1][0], 0, 0, 0);
        acc[1][1] = __builtin_amdgcn_mfma_f32_16x16x32_bf16(a1, b1, acc[1][1], 0, 0, 0);
        __syncthreads();
    }

    const int cq = lane >> 4;
    #pragma unroll
    for (int mt = 0; mt < 2; mt++) {
        #pragma unroll
        for (int nt = 0; nt < 2; nt++) {
            #pragma unroll
            for (int r = 0; r < 4; r++) {
                long long row = bm0 + wm * 32 + mt * 16 + cq * 4 + r;
                long long col = bn0 + wn * 32 + nt * 16 + r16;
                float v = acc[mt][nt][r];
                if (EPI >= 1) v += biasg[(long long)z * sBiasz + col];
                if (EPI == 1) v = fmaxf(v, 0.f);
                if (EPI == 2) v += (float)resg[(long long)z * sResz + row * (long long)ldr + col];
                if (EPI == 4)
                    ((float*)Cg)[(long long)z * sCz + row * (long long)ldc + col] = v;
                else
                    ((__bf16*)Cg)[(long long)z * sCz + row * (long long)ldc + col] = (__bf16)v;
            }
        }
    }
}

// ---------------------------------------------------------------------------
// LayerNorm: wave per row of 512, z = modality. g/b stride 512 per z.
// ---------------------------------------------------------------------------
__global__ __launch_bounds__(256)
void ln_k(const __bf16* __restrict__ in, long long inZ,
          const float* __restrict__ g, const float* __restrict__ b,
          __bf16* __restrict__ out, long long outZ, int outStride)
{
    const int row  = blockIdx.x * 4 + (threadIdx.x >> 6);
    const int lane = threadIdx.x & 63;
    const int z = blockIdx.z;
    const int j0 = lane * 8;
    bf16x8 raw = *(const bf16x8*)(in + (long long)z * inZ + (long long)row * 512 + j0);
    float x[8];
    #pragma unroll
    for (int i = 0; i < 8; i++) x[i] = (float)raw[i];
    float s = 0.f;
    #pragma unroll
    for (int i = 0; i < 8; i++) s += x[i];
    float mean = wred(s) * (1.f / 512.f);
    float vs = 0.f;
    #pragma unroll
    for (int i = 0; i < 8; i++) { float d = x[i] - mean; vs += d * d; }
    float inv = rsqrtf(wred(vs) * (1.f / 512.f) + 1e-5f);
    const float* gp = g + (long long)z * 512 + j0;
    const float* bp = b + (long long)z * 512 + j0;
    bf16x8 o;
    #pragma unroll
    for (int i = 0; i < 8; i++) o[i] = (__bf16)((x[i] - mean) * inv * gp[i] + bp[i]);
    *(bf16x8*)(out + (long long)z * outZ + (long long)row * outStride + j0) = o;
}

// ---------------------------------------------------------------------------
// GAT: wave per sample row. Wh rows [5][512] -> s1,s2 -> leaky -> softmax -> ctx
// ---------------------------------------------------------------------------
__global__ __launch_bounds__(256)
void gat_k(const __bf16* __restrict__ Wh, const float* __restrict__ ga,
           __bf16* __restrict__ ctx)
{
    const int row  = blockIdx.x * 4 + (threadIdx.x >> 6);
    const int lane = threadIdx.x & 63;
    const int j0 = lane * 8;
    float a1[8], a2[8];
    {
        float4 t0 = *(const float4*)(ga + j0);
        float4 t1 = *(const float4*)(ga + j0 + 4);
        float4 t2 = *(const float4*)(ga + 512 + j0);
        float4 t3 = *(const float4*)(ga + 512 + j0 + 4);
        a1[0]=t0.x; a1[1]=t0.y; a1[2]=t0.z; a1[3]=t0.w; a1[4]=t1.x; a1[5]=t1.y; a1[6]=t1.z; a1[7]=t1.w;
        a2[0]=t2.x; a2[1]=t2.y; a2[2]=t2.z; a2[3]=t2.w; a2[4]=t3.x; a2[5]=t3.y; a2[6]=t3.z; a2[7]=t3.w;
    }
    float wh[NMOD][8];
    #pragma unroll
    for (int n = 0; n < NMOD; n++) {
        bf16x8 r = *(const bf16x8*)(Wh + ((long long)row * NMOD + n) * 512 + j0);
        #pragma unroll
        for (int i = 0; i < 8; i++) wh[n][i] = (float)r[i];
    }
    float s1[NMOD], s2[NMOD];
    #pragma unroll
    for (int n = 0; n < NMOD; n++) {
        float p1 = 0.f, p2 = 0.f;
        #pragma unroll
        for (int i = 0; i < 8; i++) { p1 += wh[n][i] * a1[i]; p2 += wh[n][i] * a2[i]; }
        s1[n] = wred(p1); s2[n] = wred(p2);
    }
    #pragma unroll
    for (int n1 = 0; n1 < NMOD; n1++) {
        float e[NMOD]; float mx = -1e30f;
        #pragma unroll
        for (int n2 = 0; n2 < NMOD; n2++) {
            float v = s1[n1] + s2[n2];
            v = v > 0.f ? v : 0.2f * v;
            e[n2] = v; mx = fmaxf(mx, v);
        }
        float sum = 0.f;
        #pragma unroll
        for (int n2 = 0; n2 < NMOD; n2++) { e[n2] = __expf(e[n2] - mx); sum += e[n2]; }
        float isum = 1.f / sum;
        bf16x8 o;
        #pragma unroll
        for (int i = 0; i < 8; i++) {
            float c = 0.f;
            #pragma unroll
            for (int n2 = 0; n2 < NMOD; n2++) c += e[n2] * wh[n2][i];
            o[i] = (__bf16)(c * isum);
        }
        *(bf16x8*)(ctx + ((long long)row * NMOD + n1) * 512 + j0) = o;
    }
}

// ---------------------------------------------------------------------------
// MHA 1-query pooling: wave per row; lane -> (head = lane>>3, 8 d's)
// kv layout: [(b*5+n)][1024] with k in cols 0..511, v in 512..1023
// obuf: rows 0..B-1 = emo, rows B..2B-1 = pkl
// ---------------------------------------------------------------------------
__global__ __launch_bounds__(256)
void pool_k(const __bf16* __restrict__ kv, const float* __restrict__ qe,
            const float* __restrict__ qp, __bf16* __restrict__ obuf, int Bn)
{
    const int row  = blockIdx.x * 4 + (threadIdx.x >> 6);
    const int lane = threadIdx.x & 63;
    const int off = (lane >> 3) * 64 + (lane & 7) * 8;
    float kf[NMOD][8], vf[NMOD][8];
    #pragma unroll
    for (int n = 0; n < NMOD; n++) {
        bf16x8 kr = *(const bf16x8*)(kv + ((long long)row * NMOD + n) * 1024 + off);
        bf16x8 vr = *(const bf16x8*)(kv + ((long long)row * NMOD + n) * 1024 + 512 + off);
        #pragma unroll
        for (int i = 0; i < 8; i++) { kf[n][i] = (float)kr[i]; vf[n][i] = (float)vr[i]; }
    }
    #pragma unroll
    for (int qi = 0; qi < 2; qi++) {
        const float* q = qi ? qp : qe;
        float qv[8];
        {
            float4 q0 = *(const float4*)(q + off);
            float4 q1 = *(const float4*)(q + off + 4);
            qv[0]=q0.x; qv[1]=q0.y; qv[2]=q0.z; qv[3]=q0.w; qv[4]=q1.x; qv[5]=q1.y; qv[6]=q1.z; qv[7]=q1.w;
        }
        float s[NMOD];
        #pragma unroll
        for (int n = 0; n < NMOD; n++) {
            float p = 0.f;
            #pragma unroll
            for (int i = 0; i < 8; i++) p += qv[i] * kf[n][i];
            #pragma unroll
            for (int m = 1; m < 8; m <<= 1) p += __shfl_xor(p, m, 64);
            s[n] = p * 0.125f;   // / sqrt(64)
        }
        float mx = -1e30f;
        #pragma unroll
        for (int n = 0; n < NMOD; n++) mx = fmaxf(mx, s[n]);
        float sum = 0.f;
        #pragma unroll
        for (int n = 0; n < NMOD; n++) { s[n] = __expf(s[n] - mx); sum += s[n]; }
        float isum = 1.f / sum;
        bf16x8 o;
        #pragma unroll
        for (int i = 0; i < 8; i++) {
            float c = 0.f;
            #pragma unroll
            for (int n = 0; n < NMOD; n++) c += s[n] * vf[n][i];
            o[i] = (__bf16)(c * isum);
        }
        *(bf16x8*)(obuf + ((long long)(qi * Bn + row)) * 512 + off) = o;
    }
}

// ---------------------------------------------------------------------------
// mean over modality of logits/scores
// ---------------------------------------------------------------------------
__global__ __launch_bounds__(256)
void mean_k(const float* __restrict__ ela, const float* __restrict__ psa,
            float* __restrict__ mle, float* __restrict__ mlp, int Bn)
{
    const int idx = blockIdx.x * 256 + threadIdx.x;
    const int n7 = Bn * 7;
    if (idx < n7) {
        float s = 0.f;
        #pragma unroll
        for (int i = 0; i < NMOD; i++) s += ela[(long long)i * n7 + idx];
        mle[idx] = s * 0.2f;
    } else {
        const int k = idx - n7;
        float s = 0.f;
        #pragma unroll
        for (int i = 0; i < NMOD; i++) s += psa[(long long)i * Bn * 5 + k];
        mlp[k] = s * 0.2f;
    }
}

// q = query @ Wq + bq  (block 0 = emo, block 1 = pkl)
__global__ __launch_bounds__(256)
void query_k(const float* __restrict__ eq, const float* __restrict__ pq,
             const float* __restrict__ w, const float* __restrict__ bvec,
             float* __restrict__ qe, float* __restrict__ qp)
{
    const float* q = blockIdx.x ? pq : eq;
    float* o = blockIdx.x ? qp : qe;
    for (int j = threadIdx.x; j < 512; j += 256) {
        float s = bvec[j];
        for (int k = 0; k < 512; k++) s += q[k] * w[(long long)k * 1536 + j];
        o[j] = s;
    }
}

// normalize guide rows (7 emo + 5 pkl), wave per row
__global__ __launch_bounds__(256)
void guide_k(const float* __restrict__ ge, const float* __restrict__ gp,
             float* __restrict__ gne, float* __restrict__ gnp)
{
    const int r = blockIdx.x * 4 + (threadIdx.x >> 6);
    if (r >= 12) return;
    const int lane = threadIdx.x & 63;
    const int j0 = lane * 8;
    const float* src = r < 7 ? ge + (long long)r * 512 : gp + (long long)(r - 7) * 512;
    float* dst = r < 7 ? gne + (long long)r * 512 : gnp + (long long)(r - 7) * 512;
    float x[8]; float ss = 0.f;
    float4 t0 = *(const float4*)(src + j0);
    float4 t1 = *(const float4*)(src + j0 + 4);
    x[0]=t0.x; x[1]=t0.y; x[2]=t0.z; x[3]=t0.w; x[4]=t1.x; x[5]=t1.y; x[6]=t1.z; x[7]=t1.w;
    #pragma unroll
    for (int i = 0; i < 8; i++) ss += x[i] * x[i];
    float inv = 1.f / fmaxf(sqrtf(wred(ss)), 1e-8f);
    #pragma unroll
    for (int i = 0; i < 8; i++) dst[j0 + i] = x[i] * inv;
}

// ---------------------------------------------------------------------------
// Final: repr + guide-logit proj -> heads, cosine sims, sigmoids -> out[B,12]
// wave per row
// ---------------------------------------------------------------------------
__device__ inline float sigm(float x) { return 1.f / (1.f + __expf(-x)); }

__global__ __launch_bounds__(256)
void final_k(const float* __restrict__ repr, const float* __restrict__ mle,
             const float* __restrict__ mlp,
             const float* __restrict__ elp_w, const float* __restrict__ elp_b,
             const float* __restrict__ plp_w, const float* __restrict__ plp_b,
             const float* __restrict__ ehw, const float* __restrict__ ehb,
             const float* __restrict__ phw, const float* __restrict__ phb,
             const float* __restrict__ gne, const float* __restrict__ gnp,
             float* __restrict__ out, int Bn)
{
    const int row  = blockIdx.x * 4 + (threadIdx.x >> 6);
    const int lane = threadIdx.x & 63;
    const int j0 = lane * 8;
    float re[8], rp[8];
    {
        float4 e0 = *(const float4*)(repr + (long long)row * 512 + j0);
        float4 e1 = *(const float4*)(repr + (long long)row * 512 + j0 + 4);
        float4 p0 = *(const float4*)(repr + ((long long)Bn + row) * 512 + j0);
        float4 p1 = *(const float4*)(repr + ((long long)Bn + row) * 512 + j0 + 4);
        re[0]=e0.x; re[1]=e0.y; re[2]=e0.z; re[3]=e0.w; re[4]=e1.x; re[5]=e1.y; re[6]=e1.z; re[7]=e1.w;
        rp[0]=p0.x; rp[1]=p0.y; rp[2]=p0.z; rp[3]=p0.w; rp[4]=p1.x; rp[5]=p1.y; rp[6]=p1.z; rp[7]=p1.w;
    }
    float me[7], mp[5];
    #pragma unroll
    for (int c = 0; c < 7; c++) me[c] = mle[(long long)row * 7 + c];
    #pragma unroll
    for (int c = 0; c < 5; c++) mp[c] = mlp[(long long)row * 5 + c];
    #pragma unroll
    for (int i = 0; i < 8; i++) {
        const int j = j0 + i;
        float ae = elp_b[j];
        #pragma unroll
        for (int c = 0; c < 7; c++) ae += me[c] * elp_w[(long long)c * 512 + j];
        re[i] += ae;
        float ap = plp_b[j];
        #pragma unroll
        for (int c = 0; c < 5; c++) ap += mp[c] * plp_w[(long long)c * 512 + j];
        rp[i] += ap;
    }
    float ne = 0.f, np2 = 0.f;
    #pragma unroll
    for (int i = 0; i < 8; i++) { ne += re[i] * re[i]; np2 += rp[i] * rp[i]; }
    ne  = fmaxf(sqrtf(wred(ne)), 1e-8f);
    np2 = fmaxf(sqrtf(wred(np2)), 1e-8f);
    #pragma unroll
    for (int c = 0; c < 7; c++) {
        float pe = 0.f, ce = 0.f;
        #pragma unroll
        for (int i = 0; i < 8; i++) {
            const int j = j0 + i;
            pe += re[i] * ehw[(long long)j * 7 + c];
            ce += re[i] * gne[(long long)c * 512 + j];
        }
        pe = wred(pe); ce = wred(ce);
        float val = (pe + ehb[c] + ce / ne) * 0.5f;
        if (lane == c) out[(long long)row * 12 + c] = val;
    }
    #pragma unroll
    for (int c = 0; c < 5; c++) {
        float pp = 0.f, cp = 0.f;
        #pragma unroll
        for (int i = 0; i < 8; i++) {
            const int j = j0 + i;
            pp += rp[i] * phw[(long long)j * 5 + c];
            cp += rp[i] * gnp[(long long)c * 512 + j];
        }
        pp = wred(pp); cp = wred(cp);
        float val = (sigm(pp + phb[c]) + sigm(cp / np2)) * 0.5f;
        if (lane == 7 + c) out[(long long)row * 12 + 7 + c] = val;
    }
}

// ---------------------------------------------------------------------------
extern "C" void kernel_launch(void* const* d_in, const int* in_sizes, int n_in,
                              void* d_out, int out_size, void* d_ws, size_t ws_size,
                              hipStream_t stream)
{
    (void)in_sizes; (void)n_in; (void)out_size; (void)ws_size;
    const int B = BSZ;
    static const int IND[NMOD] = {2048, 1024, 1536, 512, 512};
    const float* feat[NMOD]; const float* Wp[NMOD];
    for (int i = 0; i < NMOD; i++) {
        feat[i] = (const float*)d_in[2 * i];
        Wp[i]   = (const float*)d_in[2 * i + 1];
    }
    const float* bp        = (const float*)d_in[10];
    const float* ln1_g     = (const float*)d_in[11];
    const float* ln1_b     = (const float*)d_in[12];
    const float* aW1       = (const float*)d_in[13];
    const float* ab1       = (const float*)d_in[14];
    const float* aW2       = (const float*)d_in[15];
    const float* ab2       = (const float*)d_in[16];
    const float* ln2_g     = (const float*)d_in[17];
    const float* ln2_b     = (const float*)d_in[18];
    const float* gat_W     = (const float*)d_in[19];
    const float* gat_a     = (const float*)d_in[20];
    const float* emo_q     = (const float*)d_in[21];
    const float* pkl_q     = (const float*)d_in[22];
    const float* mha_in_w  = (const float*)d_in[23];
    const float* mha_in_b  = (const float*)d_in[24];
    const float* mha_out_w = (const float*)d_in[25];
    const float* mha_out_b = (const float*)d_in[26];
    const float* ehw       = (const float*)d_in[27];
    const float* ehb       = (const float*)d_in[28];
    const float* phw       = (const float*)d_in[29];
    const float* phb       = (const float*)d_in[30];
    const float* guide_e   = (const float*)d_in[31];
    const float* guide_p   = (const float*)d_in[32];
    const float* elp_w     = (const float*)d_in[33];
    const float* elp_b     = (const float*)d_in[34];
    const float* plp_w     = (const float*)d_in[35];
    const float* plp_b     = (const float*)d_in[36];
    const float* ela       = (const float*)d_in[37];
    const float* psa       = (const float*)d_in[38];

    char* ws = (char*)d_ws;
    const size_t MB = 1u << 20;
    // R1 (0..84MB): mods bf16 [5B,512] -> ctx bf16 -> repr f32 [2B,512]
    __bf16* mods = (__bf16*)ws;
    __bf16* ctx  = mods;
    float*  repr = (float*)ws;
    // R2 (84..168MB): Wh bf16 [5B,512] -> obuf bf16 [2B,512]
    __bf16* Wh   = (__bf16*)(ws + 84 * MB);
    __bf16* obuf = Wh;
    // R3 (168..336MB): h (in-place LN1, in-place residual GEMM3) + t; later kv
    __bf16* hbuf = (__bf16*)(ws + 168 * MB);   // [5][B,512]
    __bf16* tbuf = (__bf16*)(ws + 252 * MB);   // [5][B,256]
    __bf16* kv   = (__bf16*)(ws + 168 * MB);   // [5B,1024] after stage A
    // smalls
    float* mle = (float*)(ws + 336 * MB);  // [B,7]
    float* mlp = mle + (size_t)B * 7;      // [B,5]
    float* qe  = mlp + (size_t)B * 5;      // [512]
    float* qp  = qe + 512;                 // [512]
    float* gne = qp + 512;                 // [7,512]
    float* gnp = gne + 7 * 512;            // [5,512]

    // small precomputes
    mean_k<<<dim3((B * 12) / 256), 256, 0, stream>>>(ela, psa, mle, mlp, B);
    query_k<<<dim3(2), 256, 0, stream>>>(emo_q, pkl_q, mha_in_w, mha_in_b, qe, qp);
    guide_k<<<dim3(3), 256, 0, stream>>>(guide_e, guide_p, gne, gnp);

    // Stage A: per-modality projector + adapter
    for (int i = 0; i < NMOD; i++)
        gemm_k<1, true><<<dim3(8, B / 64, 1), 256, 0, stream>>>(
            feat[i], 0, IND[i], Wp[i], 0, 512, bp + i * 512, 0,
            nullptr, 0, 0, hbuf + (long long)i * B * 512, 0, 512, IND[i]);
    ln_k<<<dim3(B / 4, 1, NMOD), 256, 0, stream>>>(
        hbuf, (long long)B * 512, ln1_g, ln1_b, hbuf, (long long)B * 512, 512);
    gemm_k<1, false><<<dim3(4, B / 64, NMOD), 256, 0, stream>>>(
        hbuf, (long long)B * 512, 512, aW1, 512LL * 256, 256, ab1, 256,
        nullptr, 0, 0, tbuf, (long long)B * 256, 256, 512);
    gemm_k<2, false><<<dim3(8, B / 64, NMOD), 256, 0, stream>>>(
        tbuf, (long long)B * 256, 256, aW2, 256LL * 512, 512, ab2, 512,
        hbuf, (long long)B * 512, 512, hbuf, (long long)B * 512, 512, 256);
    ln_k<<<dim3(B / 4, 1, NMOD), 256, 0, stream>>>(
        hbuf, (long long)B * 512, ln2_g, ln2_b, mods, 512, 2560);

    // GAT
    gemm_k<0, false><<<dim3(8, (5 * B) / 64, 1), 256, 0, stream>>>(
        mods, 0, 512, gat_W, 0, 512, nullptr, 0,
        nullptr, 0, 0, Wh, 0, 512, 512);
    gat_k<<<dim3(B / 4), 256, 0, stream>>>(Wh, gat_a, ctx);

    // K/V projection (Wk|Wv = cols 512..1535 of mha_in_w)
    gemm_k<3, false><<<dim3(16, (5 * B) / 64, 1), 256, 0, stream>>>(
        ctx, 0, 512, mha_in_w + 512, 0, 1536, mha_in_b + 512, 0,
        nullptr, 0, 0, kv, 0, 1024, 512);
    pool_k<<<dim3(B / 4), 256, 0, stream>>>(kv, qe, qp, obuf, B);

    // output projection for both pooled reps (stacked M=2B)
    gemm_k<4, false><<<dim3(8, (2 * B) / 64, 1), 256, 0, stream>>>(
        obuf, 0, 512, mha_out_w, 0, 512, mha_out_b, 0,
        nullptr, 0, 0, repr, 0, 512, 512);

    final_k<<<dim3(B / 4), 256, 0, stream>>>(
        repr, mle, mlp, elp_w, elp_b, plp_w, plp_b,
        ehw, ehb, phw, phb, gne, gnp, (float*)d_out, B);
}

// Round 4
// 1345.744 us; speedup vs baseline: 1.5722x; 1.5722x over previous
//
#include <hip/hip_runtime.h>

typedef __attribute__((ext_vector_type(8))) __bf16 bf16x8;
typedef __attribute__((ext_vector_type(4))) float f32x4;

#define NMOD 5
#define BSZ 16384

__device__ inline float wred(float v) {
    #pragma unroll
    for (int o = 32; o; o >>= 1) v += __shfl_xor(v, o, 64);
    return v;
}

__device__ __forceinline__ void glds16(const void* g, void* l) {
    __builtin_amdgcn_global_load_lds(
        (const __attribute__((address_space(1))) void*)g,
        (__attribute__((address_space(3))) void*)l, 16, 0, 0);
}

// ---------------------------------------------------------------------------
// MFMA GEMM: C[M,N] = A[M,K] @ B[K,N], B given pre-transposed bf16 Bt[N][K].
// 128x128 tile, BK=32, 256 thr = 4 waves, each wave 64x64 via 4x4 mfma16x16x32.
// Staging via global_load_lds (16B/lane); k-chunk XOR swizzle folded into the
// GLOBAL address (LDS dest is wave-uniform base + lane*16, must stay linear).
// EPI: 0 none->bf16, 1 bias+relu->bf16, 2 bias+residual->bf16, 3 bias->bf16,
//      4 bias->f32.  AF32: A is f32 (convert during staging, no glds for A).
// ---------------------------------------------------------------------------
#define BM 128
#define BN 128
#define BK 32

template<int EPI, bool AF32>
__global__ __launch_bounds__(256)
void gemm_k(const void* __restrict__ Ag, long long sAz, int lda,
            const __bf16* __restrict__ Btg, long long sBz,
            const float* __restrict__ biasg, long long sBiasz,
            const __bf16* __restrict__ resg, long long sResz, int ldr,
            void* __restrict__ Cg, long long sCz, int ldc, int K)
{
    __shared__ __bf16 As[BM * BK];
    __shared__ __bf16 Bs[BN * BK];
    const int tid  = threadIdx.x;
    const int lane = tid & 63;
    const int wv   = __builtin_amdgcn_readfirstlane(tid >> 6);
    const int wm = wv >> 1, wn = wv & 1;
    const int z = blockIdx.z;
    const long long bm0 = (long long)blockIdx.y * BM;
    const long long bn0 = (long long)blockIdx.x * BN;

    const __bf16* Ah = AF32 ? nullptr : ((const __bf16*)Ag + (long long)z * sAz);
    const float*  Af = AF32 ? ((const float*)Ag + (long long)z * sAz) : nullptr;
    const __bf16* Bt = Btg + (long long)z * sBz;

    const int sr = lane >> 2;      // staging row within 16-group
    const int sc = lane & 3;       // staging k-chunk (8 bf16 = 16B)
    const int fr = tid >> 1;       // AF32 staging: row 0..127
    const int fh = tid & 1;        // AF32: which 16-f32 half
    const int fsw = (fr >> 1) & 3;

    const int r16 = lane & 15;
    const int q4  = lane >> 4;     // k-chunk index of frag

    const f32x4 zero4 = {0.f, 0.f, 0.f, 0.f};
    f32x4 acc[4][4];
    #pragma unroll
    for (int i = 0; i < 4; i++)
        #pragma unroll
        for (int j = 0; j < 4; j++) acc[i][j] = zero4;

    for (int k0 = 0; k0 < K; k0 += BK) {
        if (AF32) {
            const float* s = Af + (bm0 + fr) * (long long)lda + k0 + fh * 16;
            float4 f0 = *(const float4*)s;
            float4 f1 = *(const float4*)(s + 4);
            float4 f2 = *(const float4*)(s + 8);
            float4 f3 = *(const float4*)(s + 12);
            bf16x8 u0, u1;
            u0[0]=(__bf16)f0.x; u0[1]=(__bf16)f0.y; u0[2]=(__bf16)f0.z; u0[3]=(__bf16)f0.w;
            u0[4]=(__bf16)f1.x; u0[5]=(__bf16)f1.y; u0[6]=(__bf16)f1.z; u0[7]=(__bf16)f1.w;
            u1[0]=(__bf16)f2.x; u1[1]=(__bf16)f2.y; u1[2]=(__bf16)f2.z; u1[3]=(__bf16)f2.w;
            u1[4]=(__bf16)f3.x; u1[5]=(__bf16)f3.y; u1[6]=(__bf16)f3.z; u1[7]=(__bf16)f3.w;
            *(bf16x8*)&As[fr * 32 + ((fh * 2    ) ^ fsw) * 8] = u0;
            *(bf16x8*)&As[fr * 32 + ((fh * 2 + 1) ^ fsw) * 8] = u1;
        } else {
            #pragma unroll
            for (int c = 0; c < 2; c++) {
                const int row = c * 64 + wv * 16 + sr;
                const int kc  = sc ^ ((row >> 1) & 3);
                glds16(Ah + (bm0 + row) * (long long)lda + k0 + kc * 8,
                       &As[(c * 64 + wv * 16) * 32]);
            }
        }
        #pragma unroll
        for (int c = 0; c < 2; c++) {
            const int row = c * 64 + wv * 16 + sr;
            const int kc  = sc ^ ((row >> 1) & 3);
            glds16(Bt + (bn0 + row) * (long long)K + k0 + kc * 8,
                   &Bs[(c * 64 + wv * 16) * 32]);
        }
        __syncthreads();
        bf16x8 av[4], bv[4];
        #pragma unroll
        for (int mt = 0; mt < 4; mt++) {
            const int m = wm * 64 + mt * 16 + r16;
            av[mt] = *(const bf16x8*)&As[m * 32 + ((q4 ^ ((m >> 1) & 3)) << 3)];
        }
        #pragma unroll
        for (int nt = 0; nt < 4; nt++) {
            const int n = wn * 64 + nt * 16 + r16;
            bv[nt] = *(const bf16x8*)&Bs[n * 32 + ((q4 ^ ((n >> 1) & 3)) << 3)];
        }
        #pragma unroll
        for (int mt = 0; mt < 4; mt++)
            #pragma unroll
            for (int nt = 0; nt < 4; nt++)
                acc[mt][nt] = __builtin_amdgcn_mfma_f32_16x16x32_bf16(
                    av[mt], bv[nt], acc[mt][nt], 0, 0, 0);
        __syncthreads();
    }

    #pragma unroll
    for (int mt = 0; mt < 4; mt++) {
        #pragma unroll
        for (int nt = 0; nt < 4; nt++) {
            #pragma unroll
            for (int r = 0; r < 4; r++) {
                long long row = bm0 + wm * 64 + mt * 16 + q4 * 4 + r;
                long long col = bn0 + wn * 64 + nt * 16 + r16;
                float v = acc[mt][nt][r];
                if (EPI >= 1) v += biasg[(long long)z * sBiasz + col];
                if (EPI == 1) v = fmaxf(v, 0.f);
                if (EPI == 2) v += (float)resg[(long long)z * sResz + row * (long long)ldr + col];
                if (EPI == 4)
                    ((float*)Cg)[(long long)z * sCz + row * (long long)ldc + col] = v;
                else
                    ((__bf16*)Cg)[(long long)z * sCz + row * (long long)ldc + col] = (__bf16)v;
            }
        }
    }
}

// ---------------------------------------------------------------------------
// Fused weight transpose+convert: dst[n*K+k] = (bf16)src[k*ldn+n], 32x32 tiles.
// ---------------------------------------------------------------------------
struct TD { const float* src; unsigned dstOff; int K, N, ldn, tile0; };
struct TDs { TD d[18]; };

__global__ __launch_bounds__(256)
void trans_k(TDs tds, __bf16* __restrict__ wb)
{
    const int bid = blockIdx.x;
    int di = 0;
    #pragma unroll
    for (int i = 1; i < 18; i++) if (bid >= tds.d[i].tile0) di = i;
    const TD t = tds.d[di];
    const int lt = bid - t.tile0;
    const int ntx = t.N >> 5;
    const int tn = lt % ntx, tk = lt / ntx;
    __shared__ float tile[32][33];
    const int c = threadIdx.x & 31, r0 = threadIdx.x >> 5;
    #pragma unroll
    for (int r = r0; r < 32; r += 8)
        tile[r][c] = t.src[(long long)(tk * 32 + r) * t.ldn + tn * 32 + c];
    __syncthreads();
    __bf16* dst = wb + t.dstOff;
    #pragma unroll
    for (int r = r0; r < 32; r += 8)
        dst[(long long)(tn * 32 + r) * t.K + tk * 32 + c] = (__bf16)tile[c][r];
}

// ---------------------------------------------------------------------------
__global__ __launch_bounds__(256)
void ln_k(const __bf16* __restrict__ in, long long inZ,
          const float* __restrict__ g, const float* __restrict__ b,
          __bf16* __restrict__ out, long long outZ, int outStride)
{
    const int row  = blockIdx.x * 4 + (threadIdx.x >> 6);
    const int lane = threadIdx.x & 63;
    const int z = blockIdx.z;
    const int j0 = lane * 8;
    bf16x8 raw = *(const bf16x8*)(in + (long long)z * inZ + (long long)row * 512 + j0);
    float x[8];
    #pragma unroll
    for (int i = 0; i < 8; i++) x[i] = (float)raw[i];
    float s = 0.f;
    #pragma unroll
    for (int i = 0; i < 8; i++) s += x[i];
    float mean = wred(s) * (1.f / 512.f);
    float vs = 0.f;
    #pragma unroll
    for (int i = 0; i < 8; i++) { float d = x[i] - mean; vs += d * d; }
    float inv = rsqrtf(wred(vs) * (1.f / 512.f) + 1e-5f);
    const float* gp = g + (long long)z * 512 + j0;
    const float* bp = b + (long long)z * 512 + j0;
    bf16x8 o;
    #pragma unroll
    for (int i = 0; i < 8; i++) o[i] = (__bf16)((x[i] - mean) * inv * gp[i] + bp[i]);
    *(bf16x8*)(out + (long long)z * outZ + (long long)row * outStride + j0) = o;
}

__global__ __launch_bounds__(256)
void gat_k(const __bf16* __restrict__ Wh, const float* __restrict__ ga,
           __bf16* __restrict__ ctx)
{
    const int row  = blockIdx.x * 4 + (threadIdx.x >> 6);
    const int lane = threadIdx.x & 63;
    const int j0 = lane * 8;
    float a1[8], a2[8];
    {
        float4 t0 = *(const float4*)(ga + j0);
        float4 t1 = *(const float4*)(ga + j0 + 4);
        float4 t2 = *(const float4*)(ga + 512 + j0);
        float4 t3 = *(const float4*)(ga + 512 + j0 + 4);
        a1[0]=t0.x; a1[1]=t0.y; a1[2]=t0.z; a1[3]=t0.w; a1[4]=t1.x; a1[5]=t1.y; a1[6]=t1.z; a1[7]=t1.w;
        a2[0]=t2.x; a2[1]=t2.y; a2[2]=t2.z; a2[3]=t2.w; a2[4]=t3.x; a2[5]=t3.y; a2[6]=t3.z; a2[7]=t3.w;
    }
    float wh[NMOD][8];
    #pragma unroll
    for (int n = 0; n < NMOD; n++) {
        bf16x8 r = *(const bf16x8*)(Wh + ((long long)row * NMOD + n) * 512 + j0);
        #pragma unroll
        for (int i = 0; i < 8; i++) wh[n][i] = (float)r[i];
    }
    float s1[NMOD], s2[NMOD];
    #pragma unroll
    for (int n = 0; n < NMOD; n++) {
        float p1 = 0.f, p2 = 0.f;
        #pragma unroll
        for (int i = 0; i < 8; i++) { p1 += wh[n][i] * a1[i]; p2 += wh[n][i] * a2[i]; }
        s1[n] = wred(p1); s2[n] = wred(p2);
    }
    #pragma unroll
    for (int n1 = 0; n1 < NMOD; n1++) {
        float e[NMOD]; float mx = -1e30f;
        #pragma unroll
        for (int n2 = 0; n2 < NMOD; n2++) {
            float v = s1[n1] + s2[n2];
            v = v > 0.f ? v : 0.2f * v;
            e[n2] = v; mx = fmaxf(mx, v);
        }
        float sum = 0.f;
        #pragma unroll
        for (int n2 = 0; n2 < NMOD; n2++) { e[n2] = __expf(e[n2] - mx); sum += e[n2]; }
        float isum = 1.f / sum;
        bf16x8 o;
        #pragma unroll
        for (int i = 0; i < 8; i++) {
            float c = 0.f;
            #pragma unroll
            for (int n2 = 0; n2 < NMOD; n2++) c += e[n2] * wh[n2][i];
            o[i] = (__bf16)(c * isum);
        }
        *(bf16x8*)(ctx + ((long long)row * NMOD + n1) * 512 + j0) = o;
    }
}

__global__ __launch_bounds__(256)
void pool_k(const __bf16* __restrict__ kv, const float* __restrict__ qe,
            const float* __restrict__ qp, __bf16* __restrict__ obuf, int Bn)
{
    const int row  = blockIdx.x * 4 + (threadIdx.x >> 6);
    const int lane = threadIdx.x & 63;
    const int off = (lane >> 3) * 64 + (lane & 7) * 8;
    float kf[NMOD][8], vf[NMOD][8];
    #pragma unroll
    for (int n = 0; n < NMOD; n++) {
        bf16x8 kr = *(const bf16x8*)(kv + ((long long)row * NMOD + n) * 1024 + off);
        bf16x8 vr = *(const bf16x8*)(kv + ((long long)row * NMOD + n) * 1024 + 512 + off);
        #pragma unroll
        for (int i = 0; i < 8; i++) { kf[n][i] = (float)kr[i]; vf[n][i] = (float)vr[i]; }
    }
    #pragma unroll
    for (int qi = 0; qi < 2; qi++) {
        const float* q = qi ? qp : qe;
        float qv[8];
        {
            float4 q0 = *(const float4*)(q + off);
            float4 q1 = *(const float4*)(q + off + 4);
            qv[0]=q0.x; qv[1]=q0.y; qv[2]=q0.z; qv[3]=q0.w; qv[4]=q1.x; qv[5]=q1.y; qv[6]=q1.z; qv[7]=q1.w;
        }
        float s[NMOD];
        #pragma unroll
        for (int n = 0; n < NMOD; n++) {
            float p = 0.f;
            #pragma unroll
            for (int i = 0; i < 8; i++) p += qv[i] * kf[n][i];
            #pragma unroll
            for (int m = 1; m < 8; m <<= 1) p += __shfl_xor(p, m, 64);
            s[n] = p * 0.125f;
        }
        float mx = -1e30f;
        #pragma unroll
        for (int n = 0; n < NMOD; n++) mx = fmaxf(mx, s[n]);
        float sum = 0.f;
        #pragma unroll
        for (int n = 0; n < NMOD; n++) { s[n] = __expf(s[n] - mx); sum += s[n]; }
        float isum = 1.f / sum;
        bf16x8 o;
        #pragma unroll
        for (int i = 0; i < 8; i++) {
            float c = 0.f;
            #pragma unroll
            for (int n = 0; n < NMOD; n++) c += s[n] * vf[n][i];
            o[i] = (__bf16)(c * isum);
        }
        *(bf16x8*)(obuf + ((long long)(qi * Bn + row)) * 512 + off) = o;
    }
}

__global__ __launch_bounds__(256)
void mean_k(const float* __restrict__ ela, const float* __restrict__ psa,
            float* __restrict__ mle, float* __restrict__ mlp, int Bn)
{
    const int idx = blockIdx.x * 256 + threadIdx.x;
    const int n7 = Bn * 7;
    if (idx < n7) {
        float s = 0.f;
        #pragma unroll
        for (int i = 0; i < NMOD; i++) s += ela[(long long)i * n7 + idx];
        mle[idx] = s * 0.2f;
    } else {
        const int k = idx - n7;
        float s = 0.f;
        #pragma unroll
        for (int i = 0; i < NMOD; i++) s += psa[(long long)i * Bn * 5 + k];
        mlp[k] = s * 0.2f;
    }
}

// wave per output j (1024 waves total)
__global__ __launch_bounds__(256)
void query_k(const float* __restrict__ eq, const float* __restrict__ pq,
             const float* __restrict__ w, const float* __restrict__ bvec,
             float* __restrict__ qe, float* __restrict__ qp)
{
    const int gw = blockIdx.x * 4 + (threadIdx.x >> 6);
    const int lane = threadIdx.x & 63;
    const int qi = gw >> 9, j = gw & 511;
    const float* q = qi ? pq : eq;
    float s = 0.f;
    for (int k = lane; k < 512; k += 64) s += q[k] * w[(long long)k * 1536 + j];
    s = wred(s);
    if (lane == 0) (qi ? qp : qe)[j] = s + bvec[j];
}

__global__ __launch_bounds__(256)
void guide_k(const float* __restrict__ ge, const float* __restrict__ gp,
             float* __restrict__ gne, float* __restrict__ gnp)
{
    const int r = blockIdx.x * 4 + (threadIdx.x >> 6);
    if (r >= 12) return;
    const int lane = threadIdx.x & 63;
    const int j0 = lane * 8;
    const float* src = r < 7 ? ge + (long long)r * 512 : gp + (long long)(r - 7) * 512;
    float* dst = r < 7 ? gne + (long long)r * 512 : gnp + (long long)(r - 7) * 512;
    float x[8]; float ss = 0.f;
    float4 t0 = *(const float4*)(src + j0);
    float4 t1 = *(const float4*)(src + j0 + 4);
    x[0]=t0.x; x[1]=t0.y; x[2]=t0.z; x[3]=t0.w; x[4]=t1.x; x[5]=t1.y; x[6]=t1.z; x[7]=t1.w;
    #pragma unroll
    for (int i = 0; i < 8; i++) ss += x[i] * x[i];
    float inv = 1.f / fmaxf(sqrtf(wred(ss)), 1e-8f);
    #pragma unroll
    for (int i = 0; i < 8; i++) dst[j0 + i] = x[i] * inv;
}

__device__ inline float sigm(float x) { return 1.f / (1.f + __expf(-x)); }

__global__ __launch_bounds__(256)
void final_k(const float* __restrict__ repr, const float* __restrict__ mle,
             const float* __restrict__ mlp,
             const float* __restrict__ elp_w, const float* __restrict__ elp_b,
             const float* __restrict__ plp_w, const float* __restrict__ plp_b,
             const float* __restrict__ ehw, const float* __restrict__ ehb,
             const float* __restrict__ phw, const float* __restrict__ phb,
             const float* __restrict__ gne, const float* __restrict__ gnp,
             float* __restrict__ out, int Bn)
{
    const int row  = blockIdx.x * 4 + (threadIdx.x >> 6);
    const int lane = threadIdx.x & 63;
    const int j0 = lane * 8;
    float re[8], rp[8];
    {
        float4 e0 = *(const float4*)(repr + (long long)row * 512 + j0);
        float4 e1 = *(const float4*)(repr + (long long)row * 512 + j0 + 4);
        float4 p0 = *(const float4*)(repr + ((long long)Bn + row) * 512 + j0);
        float4 p1 = *(const float4*)(repr + ((long long)Bn + row) * 512 + j0 + 4);
        re[0]=e0.x; re[1]=e0.y; re[2]=e0.z; re[3]=e0.w; re[4]=e1.x; re[5]=e1.y; re[6]=e1.z; re[7]=e1.w;
        rp[0]=p0.x; rp[1]=p0.y; rp[2]=p0.z; rp[3]=p0.w; rp[4]=p1.x; rp[5]=p1.y; rp[6]=p1.z; rp[7]=p1.w;
    }
    float me[7], mp[5];
    #pragma unroll
    for (int c = 0; c < 7; c++) me[c] = mle[(long long)row * 7 + c];
    #pragma unroll
    for (int c = 0; c < 5; c++) mp[c] = mlp[(long long)row * 5 + c];
    #pragma unroll
    for (int i = 0; i < 8; i++) {
        const int j = j0 + i;
        float ae = elp_b[j];
        #pragma unroll
        for (int c = 0; c < 7; c++) ae += me[c] * elp_w[(long long)c * 512 + j];
        re[i] += ae;
        float ap = plp_b[j];
        #pragma unroll
        for (int c = 0; c < 5; c++) ap += mp[c] * plp_w[(long long)c * 512 + j];
        rp[i] += ap;
    }
    float ne = 0.f, np2 = 0.f;
    #pragma unroll
    for (int i = 0; i < 8; i++) { ne += re[i] * re[i]; np2 += rp[i] * rp[i]; }
    ne  = fmaxf(sqrtf(wred(ne)), 1e-8f);
    np2 = fmaxf(sqrtf(wred(np2)), 1e-8f);
    #pragma unroll
    for (int c = 0; c < 7; c++) {
        float pe = 0.f, ce = 0.f;
        #pragma unroll
        for (int i = 0; i < 8; i++) {
            const int j = j0 + i;
            pe += re[i] * ehw[(long long)j * 7 + c];
            ce += re[i] * gne[(long long)c * 512 + j];
        }
        pe = wred(pe); ce = wred(ce);
        float val = (pe + ehb[c] + ce / ne) * 0.5f;
        if (lane == c) out[(long long)row * 12 + c] = val;
    }
    #pragma unroll
    for (int c = 0; c < 5; c++) {
        float pp = 0.f, cp = 0.f;
        #pragma unroll
        for (int i = 0; i < 8; i++) {
            const int j = j0 + i;
            pp += rp[i] * phw[(long long)j * 5 + c];
            cp += rp[i] * gnp[(long long)c * 512 + j];
        }
        pp = wred(pp); cp = wred(cp);
        float val = (sigm(pp + phb[c]) + sigm(cp / np2)) * 0.5f;
        if (lane == 7 + c) out[(long long)row * 12 + 7 + c] = val;
    }
}

// ---------------------------------------------------------------------------
extern "C" void kernel_launch(void* const* d_in, const int* in_sizes, int n_in,
                              void* d_out, int out_size, void* d_ws, size_t ws_size,
                              hipStream_t stream)
{
    (void)in_sizes; (void)n_in; (void)out_size; (void)ws_size;
    const int B = BSZ;
    static const int IND[NMOD] = {2048, 1024, 1536, 512, 512};
    const float* feat[NMOD]; const float* Wp[NMOD];
    for (int i = 0; i < NMOD; i++) {
        feat[i] = (const float*)d_in[2 * i];
        Wp[i]   = (const float*)d_in[2 * i + 1];
    }
    const float* bp        = (const float*)d_in[10];
    const float* ln1_g     = (const float*)d_in[11];
    const float* ln1_b     = (const float*)d_in[12];
    const float* aW1       = (const float*)d_in[13];
    const float* ab1       = (const float*)d_in[14];
    const float* aW2       = (const float*)d_in[15];
    const float* ab2       = (const float*)d_in[16];
    const float* ln2_g     = (const float*)d_in[17];
    const float* ln2_b     = (const float*)d_in[18];
    const float* gat_W     = (const float*)d_in[19];
    const float* gat_a     = (const float*)d_in[20];
    const float* emo_q     = (const float*)d_in[21];
    const float* pkl_q     = (const float*)d_in[22];
    const float* mha_in_w  = (const float*)d_in[23];
    const float* mha_in_b  = (const float*)d_in[24];
    const float* mha_out_w = (const float*)d_in[25];
    const float* mha_out_b = (const float*)d_in[26];
    const float* ehw       = (const float*)d_in[27];
    const float* ehb       = (const float*)d_in[28];
    const float* phw       = (const float*)d_in[29];
    const float* phb       = (const float*)d_in[30];
    const float* guide_e   = (const float*)d_in[31];
    const float* guide_p   = (const float*)d_in[32];
    const float* elp_w     = (const float*)d_in[33];
    const float* elp_b     = (const float*)d_in[34];
    const float* plp_w     = (const float*)d_in[35];
    const float* plp_b     = (const float*)d_in[36];
    const float* ela       = (const float*)d_in[37];
    const float* psa       = (const float*)d_in[38];

    char* ws = (char*)d_ws;
    const size_t MB = 1u << 20;
    // R1 (0..84MB): mods/ctx bf16 [5B,512]; later repr f32 [2B,512]
    __bf16* mods = (__bf16*)ws;
    __bf16* ctx  = mods;
    float*  repr = (float*)ws;
    // R2 (84..168MB): Wh bf16 [5B,512]; later obuf bf16 [2B,512]
    __bf16* Wh   = (__bf16*)(ws + 84 * MB);
    __bf16* obuf = Wh;
    // R3 (168..336MB): hbuf [5][B,512] + tbuf [5][B,256]; later kv [5B,1024]
    __bf16* hbuf = (__bf16*)(ws + 168 * MB);
    __bf16* tbuf = (__bf16*)(ws + 252 * MB);
    __bf16* kv   = (__bf16*)(ws + 168 * MB);
    // smalls at 336MB
    float* mle = (float*)(ws + 336 * MB);
    float* mlp = mle + (size_t)B * 7;
    float* qe  = mlp + (size_t)B * 5;
    float* qp  = qe + 512;
    float* gne = qp + 512;
    float* gnp = gne + 7 * 512;
    // bf16 transposed weights at 339MB (~10.5 MB)
    __bf16* wb = (__bf16*)(ws + 339 * MB);

    // ---- weight transpose/convert (one fused launch) ----
    TDs T; unsigned off = 0; int t0 = 0; int di = 0;
    unsigned wpOff[NMOD], a1Off, a2Off, gOff, kvOff, oOff;
    auto add = [&](const float* s, int K, int N, int ldn) {
        T.d[di].src = s; T.d[di].dstOff = off; T.d[di].K = K; T.d[di].N = N;
        T.d[di].ldn = ldn; T.d[di].tile0 = t0;
        off += (unsigned)(K * N); t0 += (K / 32) * (N / 32); di++;
    };
    for (int i = 0; i < NMOD; i++) { wpOff[i] = off; add(Wp[i], IND[i], 512, 512); }
    a1Off = off; for (int z = 0; z < NMOD; z++) add(aW1 + (long long)z * 512 * 256, 512, 256, 256);
    a2Off = off; for (int z = 0; z < NMOD; z++) add(aW2 + (long long)z * 256 * 512, 256, 512, 512);
    gOff  = off; add(gat_W, 512, 512, 512);
    kvOff = off; add(mha_in_w + 512, 512, 1024, 1536);
    oOff  = off; add(mha_out_w, 512, 512, 512);
    trans_k<<<dim3(t0), 256, 0, stream>>>(T, wb);

    // ---- small precomputes ----
    mean_k<<<dim3((B * 12) / 256), 256, 0, stream>>>(ela, psa, mle, mlp, B);
    query_k<<<dim3(256), 256, 0, stream>>>(emo_q, pkl_q, mha_in_w, mha_in_b, qe, qp);
    guide_k<<<dim3(3), 256, 0, stream>>>(guide_e, guide_p, gne, gnp);

    // ---- Stage A: projector + adapter ----
    for (int i = 0; i < NMOD; i++)
        gemm_k<1, true><<<dim3(4, B / 128, 1), 256, 0, stream>>>(
            feat[i], 0, IND[i], wb + wpOff[i], 0, bp + i * 512, 0,
            nullptr, 0, 0, hbuf + (long long)i * B * 512, 0, 512, IND[i]);
    ln_k<<<dim3(B / 4, 1, NMOD), 256, 0, stream>>>(
        hbuf, (long long)B * 512, ln1_g, ln1_b, hbuf, (long long)B * 512, 512);
    gemm_k<1, false><<<dim3(2, B / 128, NMOD), 256, 0, stream>>>(
        hbuf, (long long)B * 512, 512, wb + a1Off, 256LL * 512, ab1, 256,
        nullptr, 0, 0, tbuf, (long long)B * 256, 256, 512);
    gemm_k<2, false><<<dim3(4, B / 128, NMOD), 256, 0, stream>>>(
        tbuf, (long long)B * 256, 256, wb + a2Off, 512LL * 256, ab2, 512,
        hbuf, (long long)B * 512, 512, hbuf, (long long)B * 512, 512, 256);
    ln_k<<<dim3(B / 4, 1, NMOD), 256, 0, stream>>>(
        hbuf, (long long)B * 512, ln2_g, ln2_b, mods, 512, 2560);

    // ---- GAT ----
    gemm_k<0, false><<<dim3(4, (5 * B) / 128, 1), 256, 0, stream>>>(
        mods, 0, 512, wb + gOff, 0, nullptr, 0,
        nullptr, 0, 0, Wh, 0, 512, 512);
    gat_k<<<dim3(B / 4), 256, 0, stream>>>(Wh, gat_a, ctx);

    // ---- K/V projection + pooling ----
    gemm_k<3, false><<<dim3(8, (5 * B) / 128, 1), 256, 0, stream>>>(
        ctx, 0, 512, wb + kvOff, 0, mha_in_b + 512, 0,
        nullptr, 0, 0, kv, 0, 1024, 512);
    pool_k<<<dim3(B / 4), 256, 0, stream>>>(kv, qe, qp, obuf, B);

    // ---- output projection (stacked emo|pkl, M=2B) ----
    gemm_k<4, false><<<dim3(4, (2 * B) / 128, 1), 256, 0, stream>>>(
        obuf, 0, 512, wb + oOff, 0, mha_out_b, 0,
        nullptr, 0, 0, repr, 0, 512, 512);

    final_k<<<dim3(B / 4), 256, 0, stream>>>(
        repr, mle, mlp, elp_w, elp_b, plp_w, plp_b,
        ehw, ehb, phw, phb, gne, gnp, (float*)d_out, B);
}